// Round 15
// baseline (1792.947 us; speedup 1.0000x reference)
//
#include <hip/hip_runtime.h>

#define Bsz 4
#define Ssz 1024
#define Dsz 1024
#define Hn  16
#define DHn 64
#define Ln  6
#define Fsz 4096
#define SCALE_ 0.1767766952966369f  // 1/sqrt(32)
#define LOG2E_ 1.4426950408889634f

typedef unsigned long long u64;
typedef __attribute__((ext_vector_type(8))) short bf16x8;
typedef __attribute__((ext_vector_type(4))) float f32x4;

__device__ __forceinline__ unsigned short f2bf(float f) {
  union { float f; unsigned int u; } v; v.f = f;
  unsigned int u = v.u + 0x7fffu + ((v.u >> 16) & 1u);
  return (unsigned short)(u >> 16);
}
__device__ __forceinline__ float bf2f(unsigned short h) {
  union { unsigned int u; float f; } v; v.u = ((unsigned int)h) << 16;
  return v.f;
}
__device__ __forceinline__ void gload_lds16(const void* g, void* lds) {
  __builtin_amdgcn_global_load_lds(
      (const __attribute__((address_space(1))) unsigned int*)g,
      (__attribute__((address_space(3))) unsigned int*)lds, 16, 0, 0);
}

// ring128 swizzle: [R][32] bf16 tiles as 128B paired-row lines
__device__ __forceinline__ int swz_addr(int r, int lq) {
  int line = r >> 1;
  int u = ((r & 1) << 2) | lq;
  int s = u ^ (line & 7);
  return line * 128 + s * 16;
}

// 8-phase 256^2 kernel: khalf region = 256 rows x 32 cols bf16 (64B rows)
__device__ __forceinline__ bf16x8 frag_read(const char* base, int row, int lq) {
  return *(const bf16x8*)(base + row * 64 + ((lq ^ (row & 3)) * 16));
}

// bijective XCD swizzle for flat grid (total % 8 == 0)
__device__ __forceinline__ int xcd_swz(int flat, int total) {
  return (flat & 7) * (total >> 3) + (flat >> 3);
}

// ---------------- cos/sin tables ----------------
__global__ __launch_bounds__(256) void k_cossin(float* __restrict__ cosT, float* __restrict__ sinT) {
  int idx = blockIdx.x * 256 + threadIdx.x;
  if (idx >= Ssz * 32) return;
  int s = idx >> 5, i = idx & 31;
  float inv = powf(10000.f, -((float)(2 * i)) / 64.f);
  float f = (float)s * inv;
  cosT[idx] = cosf(f);
  sinT[idx] = sinf(f);
}

// ------- embedding gather + first LN1, fused -------
__global__ __launch_bounds__(256) void k_embed_ln(const int* __restrict__ tokens,
                                                  const float* __restrict__ emb,
                                                  const float* __restrict__ sc,
                                                  const float* __restrict__ bi,
                                                  float* __restrict__ h,
                                                  unsigned short* __restrict__ xo) {
  int rs = blockIdx.x, t = threadIdx.x;
  int tok = tokens[rs];
  float4 v = *(const float4*)&emb[(u64)tok * Dsz + t * 4];
  *(float4*)&h[(u64)rs * Dsz + t * 4] = v;
  float sm = v.x + v.y + v.z + v.w;
  float sq = v.x * v.x + v.y * v.y + v.z * v.z + v.w * v.w;
#pragma unroll
  for (int m = 1; m < 64; m <<= 1) { sm += __shfl_xor(sm, m); sq += __shfl_xor(sq, m); }
  __shared__ float r1[4], r2[4];
  if ((t & 63) == 0) { r1[t >> 6] = sm; r2[t >> 6] = sq; }
  __syncthreads();
  sm = r1[0] + r1[1] + r1[2] + r1[3];
  sq = r2[0] + r2[1] + r2[2] + r2[3];
  float mean = sm * (1.f / Dsz);
  float inv = rsqrtf(sq * (1.f / Dsz) - mean * mean + 1e-5f);
  float4 s4 = *(const float4*)&sc[t * 4];
  float4 b4 = *(const float4*)&bi[t * 4];
  ushort4 o;
  o.x = f2bf((v.x - mean) * inv * s4.x + b4.x);
  o.y = f2bf((v.y - mean) * inv * s4.y + b4.y);
  o.z = f2bf((v.z - mean) * inv * s4.z + b4.z);
  o.w = f2bf((v.w - mean) * inv * s4.w + b4.w);
  *(ushort4*)&xo[(u64)rs * Dsz + t * 4] = o;
}

// ---------------- layernorm ----------------
template <int BF16OUT>
__global__ __launch_bounds__(256) void k_layernorm(const float* __restrict__ x,
                                                   const float* __restrict__ sc,
                                                   const float* __restrict__ bi,
                                                   void* outv) {
  int row = blockIdx.x, t = threadIdx.x;
  const float* xr = x + (u64)row * Dsz;
  float4 v = *(const float4*)&xr[t * 4];
  float sm = v.x + v.y + v.z + v.w;
  float sq = v.x * v.x + v.y * v.y + v.z * v.z + v.w * v.w;
#pragma unroll
  for (int m = 1; m < 64; m <<= 1) { sm += __shfl_xor(sm, m); sq += __shfl_xor(sq, m); }
  __shared__ float r1[4], r2[4];
  if ((t & 63) == 0) { r1[t >> 6] = sm; r2[t >> 6] = sq; }
  __syncthreads();
  sm = r1[0] + r1[1] + r1[2] + r1[3];
  sq = r2[0] + r2[1] + r2[2] + r2[3];
  float mean = sm * (1.f / Dsz);
  float inv = rsqrtf(sq * (1.f / Dsz) - mean * mean + 1e-5f);
  float4 s4 = *(const float4*)&sc[t * 4];
  float4 b4 = *(const float4*)&bi[t * 4];
  float y0 = (v.x - mean) * inv * s4.x + b4.x;
  float y1 = (v.y - mean) * inv * s4.y + b4.y;
  float y2 = (v.z - mean) * inv * s4.z + b4.z;
  float y3 = (v.w - mean) * inv * s4.w + b4.w;
  if (BF16OUT) {
    ushort4 o; o.x = f2bf(y0); o.y = f2bf(y1); o.z = f2bf(y2); o.w = f2bf(y3);
    *(ushort4*)((unsigned short*)outv + (u64)row * Dsz + t * 4) = o;
  } else {
    float4 o; o.x = y0; o.y = y1; o.z = y2; o.w = y3;
    *(float4*)((float*)outv + (u64)row * Dsz + t * 4) = o;
  }
}

// ---- final LN (f32 out) + fused scores = hf @ w_score ----
__global__ __launch_bounds__(256) void k_lnf_scores(const float* __restrict__ x,
                                                    const float* __restrict__ sc,
                                                    const float* __restrict__ bi,
                                                    const float* __restrict__ wsc,
                                                    float* __restrict__ hf,
                                                    float* __restrict__ scores) {
  int row = blockIdx.x, t = threadIdx.x;
  const float* xr = x + (u64)row * Dsz;
  float4 v = *(const float4*)&xr[t * 4];
  float sm = v.x + v.y + v.z + v.w;
  float sq = v.x * v.x + v.y * v.y + v.z * v.z + v.w * v.w;
#pragma unroll
  for (int m = 1; m < 64; m <<= 1) { sm += __shfl_xor(sm, m); sq += __shfl_xor(sq, m); }
  __shared__ float r1[4], r2[4];
  if ((t & 63) == 0) { r1[t >> 6] = sm; r2[t >> 6] = sq; }
  __syncthreads();
  sm = r1[0] + r1[1] + r1[2] + r1[3];
  sq = r2[0] + r2[1] + r2[2] + r2[3];
  float mean = sm * (1.f / Dsz);
  float inv = rsqrtf(sq * (1.f / Dsz) - mean * mean + 1e-5f);
  float4 s4 = *(const float4*)&sc[t * 4];
  float4 b4 = *(const float4*)&bi[t * 4];
  float y0 = (v.x - mean) * inv * s4.x + b4.x;
  float y1 = (v.y - mean) * inv * s4.y + b4.y;
  float y2 = (v.z - mean) * inv * s4.z + b4.z;
  float y3 = (v.w - mean) * inv * s4.w + b4.w;
  float4 o; o.x = y0; o.y = y1; o.z = y2; o.w = y3;
  *(float4*)&hf[(u64)row * Dsz + t * 4] = o;
  float4 ww = *(const float4*)&wsc[t * 4];
  float dp = y0 * ww.x + y1 * ww.y + y2 * ww.z + y3 * ww.w;
#pragma unroll
  for (int m = 1; m < 64; m <<= 1) dp += __shfl_xor(dp, m);
  __shared__ float r3[4];
  if ((t & 63) == 0) r3[t >> 6] = dp;
  __syncthreads();
  if (t == 0) scores[row] = r3[0] + r3[1] + r3[2] + r3[3];
}

// ------- split-K(4) reduce + residual + next-LN1, fused -------
#define PARTN 4194304ull
__global__ __launch_bounds__(256) void k_redres_ln(const float* __restrict__ p,
                                                   float* __restrict__ h,
                                                   const float* __restrict__ sc,
                                                   const float* __restrict__ bi,
                                                   unsigned short* __restrict__ xo) {
  int row = blockIdx.x, t = threadIdx.x;
  u64 base = (u64)row * Dsz + t * 4;
  float4 a = *(float4*)&h[base];
#pragma unroll
  for (int z = 0; z < 4; ++z) {
    float4 q = *(const float4*)&p[z * PARTN + base];
    a.x += q.x; a.y += q.y; a.z += q.z; a.w += q.w;
  }
  *(float4*)&h[base] = a;
  float sm = a.x + a.y + a.z + a.w;
  float sq = a.x * a.x + a.y * a.y + a.z * a.z + a.w * a.w;
#pragma unroll
  for (int m = 1; m < 64; m <<= 1) { sm += __shfl_xor(sm, m); sq += __shfl_xor(sq, m); }
  __shared__ float r1[4], r2[4];
  if ((t & 63) == 0) { r1[t >> 6] = sm; r2[t >> 6] = sq; }
  __syncthreads();
  sm = r1[0] + r1[1] + r1[2] + r1[3];
  sq = r2[0] + r2[1] + r2[2] + r2[3];
  float mean = sm * (1.f / Dsz);
  float inv = rsqrtf(sq * (1.f / Dsz) - mean * mean + 1e-5f);
  float4 s4 = *(const float4*)&sc[t * 4];
  float4 b4 = *(const float4*)&bi[t * 4];
  ushort4 o;
  o.x = f2bf((a.x - mean) * inv * s4.x + b4.x);
  o.y = f2bf((a.y - mean) * inv * s4.y + b4.y);
  o.z = f2bf((a.z - mean) * inv * s4.z + b4.z);
  o.w = f2bf((a.w - mean) * inv * s4.w + b4.w);
  *(ushort4*)&xo[base] = o;
}

__global__ __launch_bounds__(256) void k_redres(const float* __restrict__ p,
                                                float* __restrict__ h) {
  u64 i = ((u64)blockIdx.x * 256 + threadIdx.x) * 4;
  float4 a = *(float4*)&h[i];
#pragma unroll
  for (int z = 0; z < 4; ++z) {
    float4 q = *(const float4*)&p[z * PARTN + i];
    a.x += q.x; a.y += q.y; a.z += q.z; a.w += q.w;
  }
  *(float4*)&h[i] = a;
}

// ------- weight transposes (batched over layers) -------
__global__ __launch_bounds__(256) void k_wt(const float* __restrict__ in,
                                            unsigned short* __restrict__ out, int K, int N) {
  in += (u64)blockIdx.z * K * N;
  out += (u64)blockIdx.z * K * N;
  __shared__ float tile[32][33];
  int nb = blockIdx.x * 32, kb = blockIdx.y * 32;
  int t = threadIdx.x;
  int r = t >> 3, c4 = (t & 7) * 4;
  float4 v = *(const float4*)&in[(u64)(kb + r) * N + nb + c4];
  tile[r][c4] = v.x; tile[r][c4 + 1] = v.y; tile[r][c4 + 2] = v.z; tile[r][c4 + 3] = v.w;
  __syncthreads();
  ushort4 o;
  o.x = f2bf(tile[c4][r]); o.y = f2bf(tile[c4 + 1][r]);
  o.z = f2bf(tile[c4 + 2][r]); o.w = f2bf(tile[c4 + 3][r]);
  *(ushort4*)&out[(u64)(nb + r) * K + kb + c4] = o;
}

__global__ __launch_bounds__(256) void k_wt_pair(const float* __restrict__ in,
                                                 unsigned short* __restrict__ out) {
  in += (u64)blockIdx.z * Dsz * 2 * Fsz;
  out += (u64)blockIdx.z * 2 * Fsz * Dsz;
  __shared__ float tile[32][33];
  int nb = blockIdx.x * 32, kb = blockIdx.y * 32;
  int t = threadIdx.x;
  int r = t >> 3, c4 = (t & 7) * 4;
  int s0 = nb >> 1;
  int srccol = (c4 < 16) ? (s0 + c4) : (Fsz + s0 + (c4 - 16));
  float4 v = *(const float4*)&in[(u64)(kb + r) * (2 * Fsz) + srccol];
  tile[r][c4] = v.x; tile[r][c4 + 1] = v.y; tile[r][c4 + 2] = v.z; tile[r][c4 + 3] = v.w;
  __syncthreads();
  int sc = (r >> 1) + (r & 1) * 16;
  ushort4 o;
  o.x = f2bf(tile[c4][sc]); o.y = f2bf(tile[c4 + 1][sc]);
  o.z = f2bf(tile[c4 + 2][sc]); o.w = f2bf(tile[c4 + 3][sc]);
  *(ushort4*)&out[(u64)(nb + r) * Dsz + kb + c4] = o;
}

// ------ 128x128 GEMM, 3-buffer ring ------
// EPI 2: f32 resid+C; EPI 4: fused RoPE/head-split/V-T (QKV)
template <int EPI>
__global__ __launch_bounds__(256, 3)
void k_ring(const unsigned short* __restrict__ A,
            const unsigned short* __restrict__ Bt,
            const float* resid, void* Cout,
            int M, int N, int K, int KH,
            unsigned short* qr, unsigned short* kr, unsigned short* vt,
            const float* cosT, const float* sinT) {
  __shared__ char lds[3][16384] __attribute__((aligned(16)));
  int t = threadIdx.x, w = t >> 6, l = t & 63;
  int wm = w >> 1, wn = w & 1;
  int lr = l & 15, lq = l >> 4;
  int gx = gridDim.x;
  int flat = blockIdx.y * gx + blockIdx.x;
  int swzf = xcd_swz(flat, gx * gridDim.y);
  int bm = swzf / gx, bn = swzf % gx;
  int kz = blockIdx.z;
  int NT = KH >> 5;
  int g0 = t, g1 = t + 256;
  int L0 = g0 >> 3, u0 = (g0 & 7) ^ (L0 & 7), row0 = 2 * L0 + (u0 >> 2), kc0 = (u0 & 3) * 8;
  int L1 = g1 >> 3, u1 = (g1 & 7) ^ (L1 & 7), row1 = 2 * L1 + (u1 >> 2), kc1 = (u1 & 3) * 8;
  const unsigned short* Az = A + (u64)kz * KH;
  const unsigned short* Bz = Bt + (u64)kz * KH;
  const char* Asrc0 = (const char*)(Az + (u64)(bm * 128 + row0) * K + kc0);
  const char* Asrc1 = (const char*)(Az + (u64)(bm * 128 + row1) * K + kc1);
  const char* Bsrc0 = (const char*)(Bz + (u64)(bn * 128 + row0) * K + kc0);
  const char* Bsrc1 = (const char*)(Bz + (u64)(bn * 128 + row1) * K + kc1);
  f32x4 acc[4][4];
#pragma unroll
  for (int i = 0; i < 4; ++i)
#pragma unroll
    for (int j = 0; j < 4; ++j) acc[i][j] = (f32x4){0.f, 0.f, 0.f, 0.f};
#define STG(slot, jj) { char* d_ = lds[slot]; \
    gload_lds16(Asrc0 + (u64)(jj) * 64, d_ + g0 * 16); \
    gload_lds16(Asrc1 + (u64)(jj) * 64, d_ + g1 * 16); \
    gload_lds16(Bsrc0 + (u64)(jj) * 64, d_ + 8192 + g0 * 16); \
    gload_lds16(Bsrc1 + (u64)(jj) * 64, d_ + 8192 + g1 * 16); }
  STG(0, 0); STG(1, 1);
  int cs = 0, ss = 2;
  for (int j = 0; j < NT; ++j) {
    if (j < NT - 1) asm volatile("s_waitcnt vmcnt(4)" ::: "memory");
    else            asm volatile("s_waitcnt vmcnt(0)" ::: "memory");
    __builtin_amdgcn_s_barrier();
    __builtin_amdgcn_sched_barrier(0);
    const char* Ab = lds[cs];
    const char* Bb = lds[cs] + 8192;
    if (j + 2 < NT) STG(ss, j + 2);
    bf16x8 afrag[4], bfrag[4];
#pragma unroll
    for (int ni = 0; ni < 4; ++ni)
      bfrag[ni] = *(const bf16x8*)(Bb + swz_addr(wn * 64 + ni * 16 + lr, lq));
#pragma unroll
    for (int mi = 0; mi < 4; ++mi)
      afrag[mi] = *(const bf16x8*)(Ab + swz_addr(wm * 64 + mi * 16 + lr, lq));
    __builtin_amdgcn_s_setprio(1);
#pragma unroll
    for (int mi = 0; mi < 4; ++mi)
#pragma unroll
      for (int ni = 0; ni < 4; ++ni)
        acc[mi][ni] = __builtin_amdgcn_mfma_f32_16x16x32_bf16(afrag[mi], bfrag[ni], acc[mi][ni], 0, 0, 0);
    __builtin_amdgcn_s_setprio(0);
    cs = (cs == 2) ? 0 : cs + 1;
    ss = (ss == 2) ? 0 : ss + 1;
  }
#undef STG
  if (EPI == 4) {
#pragma unroll
    for (int mi = 0; mi < 4; ++mi)
#pragma unroll
      for (int ni = 0; ni < 4; ++ni) {
        int colb = bn * 128 + wn * 64 + ni * 16;
        int sec = colb >> 10;
        int rowb = bm * 128 + wm * 64 + mi * 16 + lq * 4;
        if (sec == 2) {
          int b = rowb >> 10, s0 = rowb & 1023;
          int c = (colb & 1023) + lr, hh = c >> 6, dh = c & 63;
          ushort4 pk;
          pk.x = f2bf(acc[mi][ni][0]); pk.y = f2bf(acc[mi][ni][1]);
          pk.z = f2bf(acc[mi][ni][2]); pk.w = f2bf(acc[mi][ni][3]);
          *(ushort4*)&vt[((u64)(b * Hn + hh) * DHn + dh) * Ssz + s0] = pk;
        } else {
#pragma unroll
          for (int r = 0; r < 4; ++r) {
            float v = acc[mi][ni][r];
            float pv = __shfl_xor(v, 1);
            int row = rowb + r;
            int b = row >> 10, s = row & 1023;
            int c = (colb & 1023) + lr, hh = c >> 6, dh = c & 63;
            int ci = s * 32 + (dh >> 1);
            float cs_ = cosT[ci], sn_ = sinT[ci];
            float out = (dh & 1) ? (v * cs_ + pv * sn_) : (v * cs_ - pv * sn_);
            u64 dst = ((u64)(b * Hn + hh) * Ssz + s) * DHn + dh;
            (sec == 0 ? qr : kr)[dst] = f2bf(out);
          }
        }
      }
  } else {
#pragma unroll
    for (int mi = 0; mi < 4; ++mi)
#pragma unroll
      for (int ni = 0; ni < 4; ++ni)
#pragma unroll
        for (int r = 0; r < 4; ++r) {
          int row = bm * 128 + wm * 64 + mi * 16 + lq * 4 + r;
          int col = bn * 128 + wn * 64 + ni * 16 + lr;
          u64 idx = (u64)row * N + col;
          ((float*)Cout)[idx] = resid[idx] + acc[mi][ni][r];
        }
  }
}

// ------ 256x256 8-phase GEMM ------
#define VM8 asm volatile("s_waitcnt vmcnt(8)" ::: "memory")
#define VM4 asm volatile("s_waitcnt vmcnt(4)" ::: "memory")
#define VM0 asm volatile("s_waitcnt vmcnt(0)" ::: "memory")
#define VMN

#define STGP(buf_, kh_, j_) { \
    char* dA = lds[buf_] + (kh_) * 16384; \
    char* dB = lds[buf_] + 32768 + (kh_) * 16384; \
    u64 ko = (u64)((j_) * 64 + (kh_) * 32) * 2; \
    gload_lds16(Ab0 + ko, dA + t * 16); \
    gload_lds16(Ab1 + ko, dA + 8192 + t * 16); \
    gload_lds16(Bb0 + ko, dB + t * 16); \
    gload_lds16(Bb1 + ko, dB + 8192 + t * 16); }

#define MFMA16(mibase) \
  _Pragma("unroll") for (int mi = 0; mi < 4; ++mi) \
    _Pragma("unroll") for (int ni = 0; ni < 4; ++ni) \
      acc[mi + (mibase)][ni] = __builtin_amdgcn_mfma_f32_16x16x32_bf16(afr[mi], bfr[ni], acc[mi + (mibase)][ni], 0, 0, 0);

#define PH_COMPUTE(mibase) \
  __builtin_amdgcn_s_barrier(); \
  asm volatile("s_waitcnt lgkmcnt(0)" ::: "memory"); \
  __builtin_amdgcn_sched_barrier(0); \
  __builtin_amdgcn_s_setprio(1); \
  MFMA16(mibase); \
  __builtin_amdgcn_s_setprio(0);

#define TILE256(jj, S1, S3, G1, G3) { \
  const int buf_ = (jj) & 1, kf_ = (jj) & 1, ks2_ = kf_ ^ 1; \
  const char* LA_ = lds[buf_]; \
  const char* LB_ = lds[buf_] + 32768; \
  bf16x8 afr[4], bfr[4]; \
  _Pragma("unroll") for (int ni = 0; ni < 4; ++ni) \
    bfr[ni] = frag_read(LB_ + kf_ * 16384, wn * 64 + ni * 16 + lr, lq); \
  _Pragma("unroll") for (int mi = 0; mi < 4; ++mi) \
    afr[mi] = frag_read(LA_ + kf_ * 16384, wm * 128 + mi * 16 + lr, lq); \
  PH_COMPUTE(0); \
  __builtin_amdgcn_s_barrier(); \
  _Pragma("unroll") for (int mi = 0; mi < 4; ++mi) \
    afr[mi] = frag_read(LA_ + kf_ * 16384, wm * 128 + (mi + 4) * 16 + lr, lq); \
  if (S1) STGP(buf_ ^ 1, kf_, (jj) + 1); \
  PH_COMPUTE(4); \
  G1; \
  __builtin_amdgcn_s_barrier(); \
  _Pragma("unroll") for (int ni = 0; ni < 4; ++ni) \
    bfr[ni] = frag_read(LB_ + ks2_ * 16384, wn * 64 + ni * 16 + lr, lq); \
  _Pragma("unroll") for (int mi = 0; mi < 4; ++mi) \
    afr[mi] = frag_read(LA_ + ks2_ * 16384, wm * 128 + mi * 16 + lr, lq); \
  PH_COMPUTE(0); \
  __builtin_amdgcn_s_barrier(); \
  _Pragma("unroll") for (int mi = 0; mi < 4; ++mi) \
    afr[mi] = frag_read(LA_ + ks2_ * 16384, wm * 128 + (mi + 4) * 16 + lr, lq); \
  if (S3) STGP(buf_, kf_, (jj) + 2); \
  PH_COMPUTE(4); \
  G3; \
  __builtin_amdgcn_s_barrier(); \
}

// EPI 0: f32 split-K partial; EPI 3: paired silu-gate
template <int EPI>
__global__ __launch_bounds__(512, 2)
void k_g256(const unsigned short* __restrict__ A,
            const unsigned short* __restrict__ Bt,
            void* Cout, int M, int N, int K, int KH) {
  __shared__ char lds[2][65536] __attribute__((aligned(16)));
  int t = threadIdx.x, w = t >> 6, l = t & 63;
  int wm = w >> 2, wn = w & 3;
  int lr = l & 15, lq = l >> 4;
  int gx = gridDim.x;
  int flat = blockIdx.y * gx + blockIdx.x;
  int swzf = xcd_swz(flat, gx * gridDim.y);
  int bm = swzf / gx, bn = swzf % gx;
  int kz = blockIdx.z;
  int NT = KH >> 6;
  int r0 = t >> 2, sl = t & 3;
  int c0 = (sl ^ (r0 & 3)) * 8;
  const unsigned short* Az = A + (u64)kz * KH;
  const unsigned short* Bz = Bt + (u64)kz * KH;
  const char* Ab0 = (const char*)(Az + (u64)(bm * 256 + r0) * K + c0);
  const char* Ab1 = (const char*)(Az + (u64)(bm * 256 + 128 + r0) * K + c0);
  const char* Bb0 = (const char*)(Bz + (u64)(bn * 256 + r0) * K + c0);
  const char* Bb1 = (const char*)(Bz + (u64)(bn * 256 + 128 + r0) * K + c0);
  f32x4 acc[8][4];
#pragma unroll
  for (int i = 0; i < 8; ++i)
#pragma unroll
    for (int j = 0; j < 4; ++j) acc[i][j] = (f32x4){0.f, 0.f, 0.f, 0.f};
  STGP(0, 0, 0);
  STGP(0, 1, 0);
  STGP(1, 1, 1);
  VM8;
  __builtin_amdgcn_s_barrier();
  for (int j = 0; j < NT - 2; ++j) TILE256(j, 1, 1, VM8, VM8);
  TILE256(NT - 2, 1, 0, VM8, VM4);
  TILE256(NT - 1, 0, 0, VM0, VMN);
  u64 zoff = (u64)kz * M * N;
#pragma unroll
  for (int mi = 0; mi < 8; ++mi)
#pragma unroll
    for (int ni = 0; ni < 4; ++ni)
#pragma unroll
      for (int r = 0; r < 4; ++r) {
        int row = bm * 256 + wm * 128 + mi * 16 + lq * 4 + r;
        int col = bn * 256 + wn * 64 + ni * 16 + lr;
        float v = acc[mi][ni][r];
        if (EPI == 3) {
          float pv = __shfl_xor(v, 1);
          if ((lr & 1) == 0) {
            float res = v / (1.f + __expf(-v)) * pv;
            ((unsigned short*)Cout)[(u64)row * (N >> 1) + (col >> 1)] = f2bf(res);
          }
        } else {
          ((float*)Cout)[zoff + (u64)row * N + col] = v;
        }
      }
}

// ---------------- fused attention: QBLK=128, 8 waves, causal-aware K staging ----------------
__global__ __launch_bounds__(512) void k_attn(const unsigned short* __restrict__ qr,
                                              const unsigned short* __restrict__ kr,
                                              const unsigned short* __restrict__ vt,
                                              unsigned short* __restrict__ outp) {
  __shared__ unsigned short Klds[2][2][64 * 32] __attribute__((aligned(16)));
  __shared__ unsigned short Vlds[2][2][64 * 32] __attribute__((aligned(16)));
  __shared__ unsigned short Plds[8][16 * 64] __attribute__((aligned(16)));
  int qt = blockIdx.x, hh = blockIdx.y, b = blockIdx.z;
  int t = threadIdx.x, w = t >> 6, l = t & 63;
  int lr = l & 15, lq = l >> 4;
  u64 bh = (u64)(b * Hn + hh);
  const unsigned short* Qp = qr + bh * (Ssz * DHn);
  const unsigned short* Kp = kr + bh * (Ssz * DHn);
  const unsigned short* Vp = vt + bh * ((u64)DHn * Ssz);
  int q0 = qt * 128 + w * 16;
  int qlo_ = qt * 128, qhi_ = qt * 128 + 128;   // block q range
  bf16x8 qlo = *(const bf16x8*)&Qp[(q0 + lr) * DHn + lq * 8];
  bf16x8 qhi = *(const bf16x8*)&Qp[(q0 + lr) * DHn + 32 + lq * 8];
  int u_ = t & 255;
  int srow = u_ >> 2, scol8 = (u_ & 3) * 8;
  // needL: some chunk kc>q0 exists -> kbase >= qlo_; needH: some kc<=q0 -> kbase < qhi_
#define STAGEKV(bufi, kbase)                                                         \
  do {                                                                               \
    if (t < 256) {                                                                   \
      if ((kbase) >= qlo_)                                                           \
        gload_lds16(&Kp[((kbase) + srow) * 64 + scol8],      (char*)&Klds[bufi][0][0] + u_ * 16); \
      if ((kbase) < qhi_)                                                            \
        gload_lds16(&Kp[((kbase) + srow) * 64 + 32 + scol8], (char*)&Klds[bufi][1][0] + u_ * 16); \
    } else {                                                                         \
      gload_lds16(&Vp[(u64)srow * Ssz + (kbase) + scol8],      (char*)&Vlds[bufi][0][0] + u_ * 16); \
      gload_lds16(&Vp[(u64)srow * Ssz + (kbase) + 32 + scol8], (char*)&Vlds[bufi][1][0] + u_ * 16); \
    }                                                                                \
  } while (0)
  float m_col = -1e30f, lsum = 0.f;
  float m_row[4] = {-1e30f, -1e30f, -1e30f, -1e30f};
  f32x4 o[4];
#pragma unroll
  for (int r = 0; r < 4; ++r) o[r] = (f32x4){0.f, 0.f, 0.f, 0.f};
  char* Pw = (char*)&Plds[w][0];

  STAGEKV(0, 0);
  asm volatile("s_waitcnt vmcnt(0)" ::: "memory");
  __syncthreads();
  int buf = 0;
  const float lsc = SCALE_ * LOG2E_;
  for (int kb = 0; kb < Ssz; kb += 64) {
    if (kb + 64 < Ssz) STAGEKV(buf ^ 1, kb + 64);
    float p[4][4];
#pragma unroll
    for (int ct = 0; ct < 4; ++ct) {
      int kc = kb + ct * 16;
      f32x4 z = (f32x4){0.f, 0.f, 0.f, 0.f};
      if (kc < q0) {
        bf16x8 khi = *(const bf16x8*)&Klds[buf][1][(ct * 16 + lr) * 32 + lq * 8];
        f32x4 shi = __builtin_amdgcn_mfma_f32_16x16x32_bf16(khi, qhi, z, 0, 0, 0);
#pragma unroll
        for (int r = 0; r < 4; ++r) p[ct][r] = shi[r] * lsc;
      } else if (kc > q0) {
        bf16x8 klo = *(const bf16x8*)&Klds[buf][0][(ct * 16 + lr) * 32 + lq * 8];
        f32x4 slo = __builtin_amdgcn_mfma_f32_16x16x32_bf16(klo, qlo, z, 0, 0, 0);
#pragma unroll
        for (int r = 0; r < 4; ++r) p[ct][r] = slo[r] * lsc;
      } else {
        bf16x8 klo = *(const bf16x8*)&Klds[buf][0][(ct * 16 + lr) * 32 + lq * 8];
        bf16x8 khi = *(const bf16x8*)&Klds[buf][1][(ct * 16 + lr) * 32 + lq * 8];
        f32x4 slo = __builtin_amdgcn_mfma_f32_16x16x32_bf16(klo, qlo, z, 0, 0, 0);
        f32x4 shi = __builtin_amdgcn_mfma_f32_16x16x32_bf16(khi, qhi, z, 0, 0, 0);
        int kg0 = kc + lq * 4;
        int qg = q0 + lr;
#pragma unroll
        for (int r = 0; r < 4; ++r) p[ct][r] = (kg0 + r <= qg ? shi[r] : slo[r]) * lsc;
      }
    }
    float tm = p[0][0];
#pragma unroll
    for (int ct = 0; ct < 4; ++ct)
#pragma unroll
      for (int r = 0; r < 4; ++r) tm = fmaxf(tm, p[ct][r]);
    tm = fmaxf(tm, __shfl_xor(tm, 16));
    tm = fmaxf(tm, __shfl_xor(tm, 32));
    if (__any(tm > m_col + 8.f)) {
      float m_new = fmaxf(m_col, tm);
      lsum *= exp2f(m_col - m_new);
      m_col = m_new;
#pragma unroll
      for (int r = 0; r < 4; ++r) {
        float mr = __shfl(m_col, lq * 4 + r);
        float scf = exp2f(m_row[r] - mr);
        m_row[r] = mr;
        o[0][r] *= scf; o[1][r] *= scf; o[2][r] *= scf; o[3][r] *= scf;
      }
    }
#pragma unroll
    for (int ct = 0; ct < 4; ++ct) {
      float e0 = exp2f(p[ct][0] - m_col);
      float e1 = exp2f(p[ct][1] - m_col);
      float e2 = exp2f(p[ct][2] - m_col);
      float e3 = exp2f(p[ct][3] - m_col);
      lsum += e0 + e1 + e2 + e3;
      ushort4 pk; pk.x = f2bf(e0); pk.y = f2bf(e1); pk.z = f2bf(e2); pk.w = f2bf(e3);
      int byte_ = (lr * 128 + ct * 32 + lq * 8) ^ ((lr & 7) << 4);
      *(ushort4*)(Pw + byte_) = pk;
    }
    asm volatile("s_waitcnt lgkmcnt(0)" ::: "memory");
    __builtin_amdgcn_sched_barrier(0);
#pragma unroll
    for (int ks = 0; ks < 2; ++ks) {
      int pb = (lr * 128 + ks * 64 + lq * 16) ^ ((lr & 7) << 4);
      bf16x8 pa = *(const bf16x8*)(Pw + pb);
#pragma unroll
      for (int nt = 0; nt < 4; ++nt) {
        bf16x8 vb = *(const bf16x8*)&Vlds[buf][ks][(nt * 16 + lr) * 32 + lq * 8];
        o[nt] = __builtin_amdgcn_mfma_f32_16x16x32_bf16(pa, vb, o[nt], 0, 0, 0);
      }
    }
    asm volatile("s_waitcnt vmcnt(0)" ::: "memory");
    __syncthreads();
    buf ^= 1;
  }
  lsum += __shfl_xor(lsum, 16);
  lsum += __shfl_xor(lsum, 32);
  u64 obase = ((u64)b * Ssz) * Dsz + (u64)hh * DHn;
#pragma unroll
  for (int r = 0; r < 4; ++r) {
    float mr = __shfl(m_col, lq * 4 + r);
    float adj = exp2f(m_row[r] - mr);
    float ls = __shfl(lsum, lq * 4 + r);
    float inv = adj / ls;
    int qrow = q0 + lq * 4 + r;
#pragma unroll
    for (int nt = 0; nt < 4; ++nt)
      outp[obase + (u64)qrow * Dsz + nt * 16 + lr] = f2bf(o[nt][r] * inv);
  }
#undef STAGEKV
}

// ---------------- softmax over S ----------------
__global__ __launch_bounds__(256) void k_softmax_s(const float* __restrict__ sc,
                                                   float* __restrict__ pw) {
  int b = blockIdx.x, t = threadIdx.x;
  const float* sr = sc + b * Ssz;
  float4 v = *(const float4*)&sr[t * 4];
  float mx = fmaxf(fmaxf(v.x, v.y), fmaxf(v.z, v.w));
#pragma unroll
  for (int m = 1; m < 64; m <<= 1) mx = fmaxf(mx, __shfl_xor(mx, m));
  __shared__ float red[4];
  if ((t & 63) == 0) red[t >> 6] = mx;
  __syncthreads();
  mx = fmaxf(fmaxf(red[0], red[1]), fmaxf(red[2], red[3]));
  float e0 = __expf(v.x - mx), e1 = __expf(v.y - mx), e2 = __expf(v.z - mx), e3 = __expf(v.w - mx);
  float sm = e0 + e1 + e2 + e3;
#pragma unroll
  for (int m = 1; m < 64; m <<= 1) sm += __shfl_xor(sm, m);
  __shared__ float red2[4];
  if ((t & 63) == 0) red2[t >> 6] = sm;
  __syncthreads();
  sm = red2[0] + red2[1] + red2[2] + red2[3];
  float inv = 1.f / sm;
  float4 o; o.x = e0 * inv; o.y = e1 * inv; o.z = e2 * inv; o.w = e3 * inv;
  *(float4*)&pw[b * Ssz + t * 4] = o;
}

// ------- pooled, two-stage -------
__global__ __launch_bounds__(256) void k_pool1(const float* __restrict__ hf,
                                               const float* __restrict__ pw,
                                               float* __restrict__ part) {
  int d = blockIdx.x * 256 + threadIdx.x;
  int b = blockIdx.y, scn = blockIdx.z;
  const float* pwb = pw + b * Ssz + scn * 64;
  const float* hb = hf + ((u64)(b * Ssz + scn * 64)) * Dsz + d;
  float acc = 0.f;
#pragma unroll 4
  for (int s = 0; s < 64; ++s) acc += pwb[s] * hb[(u64)s * Dsz];
  part[(u64)(b * 16 + scn) * Dsz + d] = acc;
}
__global__ __launch_bounds__(256) void k_pool2(const float* __restrict__ part,
                                               float* __restrict__ pooled) {
  int d = blockIdx.x * 256 + threadIdx.x;
  int b = blockIdx.y;
  float acc = 0.f;
#pragma unroll
  for (int i = 0; i < 16; ++i) acc += part[(u64)(b * 16 + i) * Dsz + d];
  pooled[b * Dsz + d] = acc;
}

// ------- classifier, split-K two-stage -------
__global__ __launch_bounds__(256) void k_cls1(const float* __restrict__ pooled,
                                              const float* __restrict__ wcls,
                                              float* __restrict__ part) {
  int n = blockIdx.x * 64 + (threadIdx.x & 63);
  int b = threadIdx.x >> 6;
  int kz = blockIdx.y;
  const float* pb = pooled + b * Dsz + kz * 128;
  const float* wb = wcls + (u64)(kz * 128) * Ssz + n;
  float acc = 0.f;
#pragma unroll 4
  for (int k = 0; k < 128; ++k) acc += pb[k] * wb[(u64)k * Ssz];
  part[(u64)(kz * 4 + b) * Ssz + n] = acc;
}
__global__ __launch_bounds__(256) void k_cls2(const float* __restrict__ part,
                                              float* __restrict__ outp) {
  int n = blockIdx.x * 64 + (threadIdx.x & 63);
  int b = threadIdx.x >> 6;
  float acc = 0.f;
#pragma unroll
  for (int kz = 0; kz < 8; ++kz) acc += part[(u64)(kz * 4 + b) * Ssz + n];
  outp[b * Ssz + n] = acc;
}

extern "C" void kernel_launch(void* const* d_in, const int* in_sizes, int n_in,
                              void* d_out, int out_size, void* d_ws, size_t ws_size,
                              hipStream_t stream) {
  (void)in_sizes; (void)n_in; (void)out_size; (void)ws_size;
  const int*   tokens  = (const int*)  d_in[0];
  const float* tok_emb = (const float*)d_in[1];
  const float* ln1_s   = (const float*)d_in[2];
  const float* ln1_b   = (const float*)d_in[3];
  const float* w_qkv   = (const float*)d_in[4];
  const float* w_proj  = (const float*)d_in[5];
  const float* ln2_s   = (const float*)d_in[6];
  const float* ln2_b   = (const float*)d_in[7];
  const float* w_in    = (const float*)d_in[8];
  const float* w_out   = (const float*)d_in[9];
  const float* lnf_s   = (const float*)d_in[10];
  const float* lnf_b   = (const float*)d_in[11];
  const float* w_score = (const float*)d_in[12];
  const float* w_cls   = (const float*)d_in[13];
  float* outp = (float*)d_out;
  char* ws = (char*)d_ws;

  unsigned short* q_r    = (unsigned short*)(ws + 25165824ull);
  unsigned short* k_r    = (unsigned short*)(ws + 33554432ull);
  unsigned short* v_t    = (unsigned short*)(ws + 41943040ull);
  unsigned short* a_out  = (unsigned short*)(ws + 50331648ull);
  float*          hf     = (float*)(ws + 0);
  unsigned short* x_ln   = (unsigned short*)(ws + 67108864ull);
  unsigned short* mbuf   = (unsigned short*)(ws + 75497472ull);
  float*          h      = (float*)(ws + 109051904ull);
  float* cosT    = (float*)(ws + 125829120ull);
  float* sinT    = (float*)(ws + 125960192ull);
  float* scoresb = (float*)(ws + 126091264ull);
  float* pwb     = (float*)(ws + 126107648ull);
  float* pooledb = (float*)(ws + 126124032ull);
  float* poolpart= (float*)(ws + 126140416ull);
  float* clspart = (float*)(ws + 126402560ull);
  unsigned short* wqkv_t = (unsigned short*)(ws + 134217728ull);
  unsigned short* wproj_t= (unsigned short*)(ws + 171966464ull);
  unsigned short* win_t  = (unsigned short*)(ws + 184549376ull);
  unsigned short* wout_t = (unsigned short*)(ws + 285212672ull);
  float* skpart  = (float*)(ws + 335544320ull);

  dim3 blk(256);
  k_cossin<<<dim3(128), blk, 0, stream>>>(cosT, sinT);
  k_embed_ln<<<dim3(4096), blk, 0, stream>>>(tokens, tok_emb, ln1_s, ln1_b, h, x_ln);
  k_wt<<<dim3(96, 32, 6), blk, 0, stream>>>(w_qkv, wqkv_t, Dsz, 3 * Dsz);
  k_wt<<<dim3(32, 32, 6), blk, 0, stream>>>(w_proj, wproj_t, Dsz, Dsz);
  k_wt_pair<<<dim3(256, 32, 6), blk, 0, stream>>>(w_in, win_t);
  k_wt<<<dim3(32, 128, 6), blk, 0, stream>>>(w_out, wout_t, Fsz, Dsz);

  for (int l = 0; l < Ln; ++l) {
    unsigned short* wq = wqkv_t + (u64)l * 3145728ull;
    unsigned short* wp = wproj_t + (u64)l * 1048576ull;
    unsigned short* wi = win_t + (u64)l * 8388608ull;
    unsigned short* wo = wout_t + (u64)l * 4194304ull;
    k_ring<4><<<dim3(24, 32), blk, 0, stream>>>(x_ln, wq, nullptr, nullptr,
        4096, 3072, 1024, 1024, q_r, k_r, v_t, cosT, sinT);
    k_attn<<<dim3(8, 16, 4), dim3(512), 0, stream>>>(q_r, k_r, v_t, a_out);
    k_ring<2><<<dim3(8, 32), blk, 0, stream>>>(a_out, wp, h, (void*)h,
        4096, 1024, 1024, 1024, nullptr, nullptr, nullptr, nullptr, nullptr);
    k_layernorm<1><<<dim3(4096), blk, 0, stream>>>(h, ln2_s + l * Dsz, ln2_b + l * Dsz, (void*)x_ln);
    k_g256<3><<<dim3(32, 16), dim3(512), 0, stream>>>(x_ln, wi, (void*)mbuf,
        4096, 8192, 1024, 1024);
    k_g256<0><<<dim3(4, 16, 4), dim3(512), 0, stream>>>(mbuf, wo, (void*)skpart,
        4096, 1024, 4096, 1024);
    if (l < Ln - 1)
      k_redres_ln<<<dim3(4096), blk, 0, stream>>>(skpart, h,
          ln1_s + (l + 1) * Dsz, ln1_b + (l + 1) * Dsz, x_ln);
    else
      k_redres<<<dim3(4096), blk, 0, stream>>>(skpart, h);
  }

  k_lnf_scores<<<dim3(4096), blk, 0, stream>>>(h, lnf_s, lnf_b, w_score, hf, scoresb);
  k_softmax_s<<<dim3(4), blk, 0, stream>>>(scoresb, pwb);
  k_pool1<<<dim3(4, 4, 16), blk, 0, stream>>>(hf, pwb, poolpart);
  k_pool2<<<dim3(4, 4), blk, 0, stream>>>(poolpart, pooledb);
  k_cls1<<<dim3(16, 8), blk, 0, stream>>>(pooledb, w_cls, clspart);
  k_cls2<<<dim3(16), blk, 0, stream>>>(clspart, outp);
}

// Round 16
// 1785.974 us; speedup vs baseline: 1.0039x; 1.0039x over previous
//
#include <hip/hip_runtime.h>

#define Bsz 4
#define Ssz 1024
#define Dsz 1024
#define Hn  16
#define DHn 64
#define Ln  6
#define Fsz 4096
#define SCALE_ 0.1767766952966369f  // 1/sqrt(32)
#define LOG2E_ 1.4426950408889634f

typedef unsigned long long u64;
typedef __attribute__((ext_vector_type(8))) short bf16x8;
typedef __attribute__((ext_vector_type(4))) float f32x4;

__device__ __forceinline__ unsigned short f2bf(float f) {
  union { float f; unsigned int u; } v; v.f = f;
  unsigned int u = v.u + 0x7fffu + ((v.u >> 16) & 1u);
  return (unsigned short)(u >> 16);
}
__device__ __forceinline__ float bf2f(unsigned short h) {
  union { unsigned int u; float f; } v; v.u = ((unsigned int)h) << 16;
  return v.f;
}
__device__ __forceinline__ void gload_lds16(const void* g, void* lds) {
  __builtin_amdgcn_global_load_lds(
      (const __attribute__((address_space(1))) unsigned int*)g,
      (__attribute__((address_space(3))) unsigned int*)lds, 16, 0, 0);
}

// ring128 swizzle: [R][32] bf16 tiles as 128B paired-row lines
__device__ __forceinline__ int swz_addr(int r, int lq) {
  int line = r >> 1;
  int u = ((r & 1) << 2) | lq;
  int s = u ^ (line & 7);
  return line * 128 + s * 16;
}

// 8-phase 256^2 kernel: khalf region = 256 rows x 32 cols bf16 (64B rows)
__device__ __forceinline__ bf16x8 frag_read(const char* base, int row, int lq) {
  return *(const bf16x8*)(base + row * 64 + ((lq ^ (row & 3)) * 16));
}

// bijective XCD swizzle for flat grid (total % 8 == 0)
__device__ __forceinline__ int xcd_swz(int flat, int total) {
  return (flat & 7) * (total >> 3) + (flat >> 3);
}

// ---------------- cos/sin tables ----------------
__global__ __launch_bounds__(256) void k_cossin(float* __restrict__ cosT, float* __restrict__ sinT) {
  int idx = blockIdx.x * 256 + threadIdx.x;
  if (idx >= Ssz * 32) return;
  int s = idx >> 5, i = idx & 31;
  float inv = powf(10000.f, -((float)(2 * i)) / 64.f);
  float f = (float)s * inv;
  cosT[idx] = cosf(f);
  sinT[idx] = sinf(f);
}

// ------- embedding gather + first LN1, fused -------
__global__ __launch_bounds__(256) void k_embed_ln(const int* __restrict__ tokens,
                                                  const float* __restrict__ emb,
                                                  const float* __restrict__ sc,
                                                  const float* __restrict__ bi,
                                                  float* __restrict__ h,
                                                  unsigned short* __restrict__ xo) {
  int rs = blockIdx.x, t = threadIdx.x;
  int tok = tokens[rs];
  float4 v = *(const float4*)&emb[(u64)tok * Dsz + t * 4];
  *(float4*)&h[(u64)rs * Dsz + t * 4] = v;
  float sm = v.x + v.y + v.z + v.w;
  float sq = v.x * v.x + v.y * v.y + v.z * v.z + v.w * v.w;
#pragma unroll
  for (int m = 1; m < 64; m <<= 1) { sm += __shfl_xor(sm, m); sq += __shfl_xor(sq, m); }
  __shared__ float r1[4], r2[4];
  if ((t & 63) == 0) { r1[t >> 6] = sm; r2[t >> 6] = sq; }
  __syncthreads();
  sm = r1[0] + r1[1] + r1[2] + r1[3];
  sq = r2[0] + r2[1] + r2[2] + r2[3];
  float mean = sm * (1.f / Dsz);
  float inv = rsqrtf(sq * (1.f / Dsz) - mean * mean + 1e-5f);
  float4 s4 = *(const float4*)&sc[t * 4];
  float4 b4 = *(const float4*)&bi[t * 4];
  ushort4 o;
  o.x = f2bf((v.x - mean) * inv * s4.x + b4.x);
  o.y = f2bf((v.y - mean) * inv * s4.y + b4.y);
  o.z = f2bf((v.z - mean) * inv * s4.z + b4.z);
  o.w = f2bf((v.w - mean) * inv * s4.w + b4.w);
  *(ushort4*)&xo[(u64)rs * Dsz + t * 4] = o;
}

// ---------------- layernorm ----------------
template <int BF16OUT>
__global__ __launch_bounds__(256) void k_layernorm(const float* __restrict__ x,
                                                   const float* __restrict__ sc,
                                                   const float* __restrict__ bi,
                                                   void* outv) {
  int row = blockIdx.x, t = threadIdx.x;
  const float* xr = x + (u64)row * Dsz;
  float4 v = *(const float4*)&xr[t * 4];
  float sm = v.x + v.y + v.z + v.w;
  float sq = v.x * v.x + v.y * v.y + v.z * v.z + v.w * v.w;
#pragma unroll
  for (int m = 1; m < 64; m <<= 1) { sm += __shfl_xor(sm, m); sq += __shfl_xor(sq, m); }
  __shared__ float r1[4], r2[4];
  if ((t & 63) == 0) { r1[t >> 6] = sm; r2[t >> 6] = sq; }
  __syncthreads();
  sm = r1[0] + r1[1] + r1[2] + r1[3];
  sq = r2[0] + r2[1] + r2[2] + r2[3];
  float mean = sm * (1.f / Dsz);
  float inv = rsqrtf(sq * (1.f / Dsz) - mean * mean + 1e-5f);
  float4 s4 = *(const float4*)&sc[t * 4];
  float4 b4 = *(const float4*)&bi[t * 4];
  float y0 = (v.x - mean) * inv * s4.x + b4.x;
  float y1 = (v.y - mean) * inv * s4.y + b4.y;
  float y2 = (v.z - mean) * inv * s4.z + b4.z;
  float y3 = (v.w - mean) * inv * s4.w + b4.w;
  if (BF16OUT) {
    ushort4 o; o.x = f2bf(y0); o.y = f2bf(y1); o.z = f2bf(y2); o.w = f2bf(y3);
    *(ushort4*)((unsigned short*)outv + (u64)row * Dsz + t * 4) = o;
  } else {
    float4 o; o.x = y0; o.y = y1; o.z = y2; o.w = y3;
    *(float4*)((float*)outv + (u64)row * Dsz + t * 4) = o;
  }
}

// ---- final LN (f32 out) + fused scores = hf @ w_score ----
__global__ __launch_bounds__(256) void k_lnf_scores(const float* __restrict__ x,
                                                    const float* __restrict__ sc,
                                                    const float* __restrict__ bi,
                                                    const float* __restrict__ wsc,
                                                    float* __restrict__ hf,
                                                    float* __restrict__ scores) {
  int row = blockIdx.x, t = threadIdx.x;
  const float* xr = x + (u64)row * Dsz;
  float4 v = *(const float4*)&xr[t * 4];
  float sm = v.x + v.y + v.z + v.w;
  float sq = v.x * v.x + v.y * v.y + v.z * v.z + v.w * v.w;
#pragma unroll
  for (int m = 1; m < 64; m <<= 1) { sm += __shfl_xor(sm, m); sq += __shfl_xor(sq, m); }
  __shared__ float r1[4], r2[4];
  if ((t & 63) == 0) { r1[t >> 6] = sm; r2[t >> 6] = sq; }
  __syncthreads();
  sm = r1[0] + r1[1] + r1[2] + r1[3];
  sq = r2[0] + r2[1] + r2[2] + r2[3];
  float mean = sm * (1.f / Dsz);
  float inv = rsqrtf(sq * (1.f / Dsz) - mean * mean + 1e-5f);
  float4 s4 = *(const float4*)&sc[t * 4];
  float4 b4 = *(const float4*)&bi[t * 4];
  float y0 = (v.x - mean) * inv * s4.x + b4.x;
  float y1 = (v.y - mean) * inv * s4.y + b4.y;
  float y2 = (v.z - mean) * inv * s4.z + b4.z;
  float y3 = (v.w - mean) * inv * s4.w + b4.w;
  float4 o; o.x = y0; o.y = y1; o.z = y2; o.w = y3;
  *(float4*)&hf[(u64)row * Dsz + t * 4] = o;
  float4 ww = *(const float4*)&wsc[t * 4];
  float dp = y0 * ww.x + y1 * ww.y + y2 * ww.z + y3 * ww.w;
#pragma unroll
  for (int m = 1; m < 64; m <<= 1) dp += __shfl_xor(dp, m);
  __shared__ float r3[4];
  if ((t & 63) == 0) r3[t >> 6] = dp;
  __syncthreads();
  if (t == 0) scores[row] = r3[0] + r3[1] + r3[2] + r3[3];
}

// ------- split-K(4) reduce + residual + next-LN1, fused -------
#define PARTN 4194304ull
__global__ __launch_bounds__(256) void k_redres_ln(const float* __restrict__ p,
                                                   float* __restrict__ h,
                                                   const float* __restrict__ sc,
                                                   const float* __restrict__ bi,
                                                   unsigned short* __restrict__ xo) {
  int row = blockIdx.x, t = threadIdx.x;
  u64 base = (u64)row * Dsz + t * 4;
  float4 a = *(float4*)&h[base];
#pragma unroll
  for (int z = 0; z < 4; ++z) {
    float4 q = *(const float4*)&p[z * PARTN + base];
    a.x += q.x; a.y += q.y; a.z += q.z; a.w += q.w;
  }
  *(float4*)&h[base] = a;
  float sm = a.x + a.y + a.z + a.w;
  float sq = a.x * a.x + a.y * a.y + a.z * a.z + a.w * a.w;
#pragma unroll
  for (int m = 1; m < 64; m <<= 1) { sm += __shfl_xor(sm, m); sq += __shfl_xor(sq, m); }
  __shared__ float r1[4], r2[4];
  if ((t & 63) == 0) { r1[t >> 6] = sm; r2[t >> 6] = sq; }
  __syncthreads();
  sm = r1[0] + r1[1] + r1[2] + r1[3];
  sq = r2[0] + r2[1] + r2[2] + r2[3];
  float mean = sm * (1.f / Dsz);
  float inv = rsqrtf(sq * (1.f / Dsz) - mean * mean + 1e-5f);
  float4 s4 = *(const float4*)&sc[t * 4];
  float4 b4 = *(const float4*)&bi[t * 4];
  ushort4 o;
  o.x = f2bf((a.x - mean) * inv * s4.x + b4.x);
  o.y = f2bf((a.y - mean) * inv * s4.y + b4.y);
  o.z = f2bf((a.z - mean) * inv * s4.z + b4.z);
  o.w = f2bf((a.w - mean) * inv * s4.w + b4.w);
  *(ushort4*)&xo[base] = o;
}

__global__ __launch_bounds__(256) void k_redres(const float* __restrict__ p,
                                                float* __restrict__ h) {
  u64 i = ((u64)blockIdx.x * 256 + threadIdx.x) * 4;
  float4 a = *(float4*)&h[i];
#pragma unroll
  for (int z = 0; z < 4; ++z) {
    float4 q = *(const float4*)&p[z * PARTN + i];
    a.x += q.x; a.y += q.y; a.z += q.z; a.w += q.w;
  }
  *(float4*)&h[i] = a;
}

// ------- weight transposes (batched over layers) -------
__global__ __launch_bounds__(256) void k_wt(const float* __restrict__ in,
                                            unsigned short* __restrict__ out, int K, int N) {
  in += (u64)blockIdx.z * K * N;
  out += (u64)blockIdx.z * K * N;
  __shared__ float tile[32][33];
  int nb = blockIdx.x * 32, kb = blockIdx.y * 32;
  int t = threadIdx.x;
  int r = t >> 3, c4 = (t & 7) * 4;
  float4 v = *(const float4*)&in[(u64)(kb + r) * N + nb + c4];
  tile[r][c4] = v.x; tile[r][c4 + 1] = v.y; tile[r][c4 + 2] = v.z; tile[r][c4 + 3] = v.w;
  __syncthreads();
  ushort4 o;
  o.x = f2bf(tile[c4][r]); o.y = f2bf(tile[c4 + 1][r]);
  o.z = f2bf(tile[c4 + 2][r]); o.w = f2bf(tile[c4 + 3][r]);
  *(ushort4*)&out[(u64)(nb + r) * K + kb + c4] = o;
}

__global__ __launch_bounds__(256) void k_wt_pair(const float* __restrict__ in,
                                                 unsigned short* __restrict__ out) {
  in += (u64)blockIdx.z * Dsz * 2 * Fsz;
  out += (u64)blockIdx.z * 2 * Fsz * Dsz;
  __shared__ float tile[32][33];
  int nb = blockIdx.x * 32, kb = blockIdx.y * 32;
  int t = threadIdx.x;
  int r = t >> 3, c4 = (t & 7) * 4;
  int s0 = nb >> 1;
  int srccol = (c4 < 16) ? (s0 + c4) : (Fsz + s0 + (c4 - 16));
  float4 v = *(const float4*)&in[(u64)(kb + r) * (2 * Fsz) + srccol];
  tile[r][c4] = v.x; tile[r][c4 + 1] = v.y; tile[r][c4 + 2] = v.z; tile[r][c4 + 3] = v.w;
  __syncthreads();
  int sc = (r >> 1) + (r & 1) * 16;
  ushort4 o;
  o.x = f2bf(tile[c4][sc]); o.y = f2bf(tile[c4 + 1][sc]);
  o.z = f2bf(tile[c4 + 2][sc]); o.w = f2bf(tile[c4 + 3][sc]);
  *(ushort4*)&out[(u64)(nb + r) * Dsz + kb + c4] = o;
}

// ------ 128x128 GEMM, 3-buffer ring ------
// EPI 2: f32 resid+C; EPI 4: fused RoPE/head-split/V-T (QKV)
template <int EPI>
__global__ __launch_bounds__(256, 3)
void k_ring(const unsigned short* __restrict__ A,
            const unsigned short* __restrict__ Bt,
            const float* resid, void* Cout,
            int M, int N, int K, int KH,
            unsigned short* qr, unsigned short* kr, unsigned short* vt,
            const float* cosT, const float* sinT) {
  __shared__ char lds[3][16384] __attribute__((aligned(16)));
  int t = threadIdx.x, w = t >> 6, l = t & 63;
  int wm = w >> 1, wn = w & 1;
  int lr = l & 15, lq = l >> 4;
  int gx = gridDim.x;
  int flat = blockIdx.y * gx + blockIdx.x;
  int swzf = xcd_swz(flat, gx * gridDim.y);
  int bm = swzf / gx, bn = swzf % gx;
  int kz = blockIdx.z;
  int NT = KH >> 5;
  int g0 = t, g1 = t + 256;
  int L0 = g0 >> 3, u0 = (g0 & 7) ^ (L0 & 7), row0 = 2 * L0 + (u0 >> 2), kc0 = (u0 & 3) * 8;
  int L1 = g1 >> 3, u1 = (g1 & 7) ^ (L1 & 7), row1 = 2 * L1 + (u1 >> 2), kc1 = (u1 & 3) * 8;
  const unsigned short* Az = A + (u64)kz * KH;
  const unsigned short* Bz = Bt + (u64)kz * KH;
  const char* Asrc0 = (const char*)(Az + (u64)(bm * 128 + row0) * K + kc0);
  const char* Asrc1 = (const char*)(Az + (u64)(bm * 128 + row1) * K + kc1);
  const char* Bsrc0 = (const char*)(Bz + (u64)(bn * 128 + row0) * K + kc0);
  const char* Bsrc1 = (const char*)(Bz + (u64)(bn * 128 + row1) * K + kc1);
  f32x4 acc[4][4];
#pragma unroll
  for (int i = 0; i < 4; ++i)
#pragma unroll
    for (int j = 0; j < 4; ++j) acc[i][j] = (f32x4){0.f, 0.f, 0.f, 0.f};
#define STG(slot, jj) { char* d_ = lds[slot]; \
    gload_lds16(Asrc0 + (u64)(jj) * 64, d_ + g0 * 16); \
    gload_lds16(Asrc1 + (u64)(jj) * 64, d_ + g1 * 16); \
    gload_lds16(Bsrc0 + (u64)(jj) * 64, d_ + 8192 + g0 * 16); \
    gload_lds16(Bsrc1 + (u64)(jj) * 64, d_ + 8192 + g1 * 16); }
  STG(0, 0); STG(1, 1);
  int cs = 0, ss = 2;
  for (int j = 0; j < NT; ++j) {
    if (j < NT - 1) asm volatile("s_waitcnt vmcnt(4)" ::: "memory");
    else            asm volatile("s_waitcnt vmcnt(0)" ::: "memory");
    __builtin_amdgcn_s_barrier();
    __builtin_amdgcn_sched_barrier(0);
    const char* Ab = lds[cs];
    const char* Bb = lds[cs] + 8192;
    if (j + 2 < NT) STG(ss, j + 2);
    bf16x8 afrag[4], bfrag[4];
#pragma unroll
    for (int ni = 0; ni < 4; ++ni)
      bfrag[ni] = *(const bf16x8*)(Bb + swz_addr(wn * 64 + ni * 16 + lr, lq));
#pragma unroll
    for (int mi = 0; mi < 4; ++mi)
      afrag[mi] = *(const bf16x8*)(Ab + swz_addr(wm * 64 + mi * 16 + lr, lq));
    __builtin_amdgcn_s_setprio(1);
#pragma unroll
    for (int mi = 0; mi < 4; ++mi)
#pragma unroll
      for (int ni = 0; ni < 4; ++ni)
        acc[mi][ni] = __builtin_amdgcn_mfma_f32_16x16x32_bf16(afrag[mi], bfrag[ni], acc[mi][ni], 0, 0, 0);
    __builtin_amdgcn_s_setprio(0);
    cs = (cs == 2) ? 0 : cs + 1;
    ss = (ss == 2) ? 0 : ss + 1;
  }
#undef STG
  if (EPI == 4) {
#pragma unroll
    for (int mi = 0; mi < 4; ++mi)
#pragma unroll
      for (int ni = 0; ni < 4; ++ni) {
        int colb = bn * 128 + wn * 64 + ni * 16;
        int sec = colb >> 10;
        int rowb = bm * 128 + wm * 64 + mi * 16 + lq * 4;
        if (sec == 2) {
          int b = rowb >> 10, s0 = rowb & 1023;
          int c = (colb & 1023) + lr, hh = c >> 6, dh = c & 63;
          ushort4 pk;
          pk.x = f2bf(acc[mi][ni][0]); pk.y = f2bf(acc[mi][ni][1]);
          pk.z = f2bf(acc[mi][ni][2]); pk.w = f2bf(acc[mi][ni][3]);
          *(ushort4*)&vt[((u64)(b * Hn + hh) * DHn + dh) * Ssz + s0] = pk;
        } else {
#pragma unroll
          for (int r = 0; r < 4; ++r) {
            float v = acc[mi][ni][r];
            float pv = __shfl_xor(v, 1);
            int row = rowb + r;
            int b = row >> 10, s = row & 1023;
            int c = (colb & 1023) + lr, hh = c >> 6, dh = c & 63;
            int ci = s * 32 + (dh >> 1);
            float cs_ = cosT[ci], sn_ = sinT[ci];
            float out = (dh & 1) ? (v * cs_ + pv * sn_) : (v * cs_ - pv * sn_);
            u64 dst = ((u64)(b * Hn + hh) * Ssz + s) * DHn + dh;
            (sec == 0 ? qr : kr)[dst] = f2bf(out);
          }
        }
      }
  } else {
#pragma unroll
    for (int mi = 0; mi < 4; ++mi)
#pragma unroll
      for (int ni = 0; ni < 4; ++ni)
#pragma unroll
        for (int r = 0; r < 4; ++r) {
          int row = bm * 128 + wm * 64 + mi * 16 + lq * 4 + r;
          int col = bn * 128 + wn * 64 + ni * 16 + lr;
          u64 idx = (u64)row * N + col;
          ((float*)Cout)[idx] = resid[idx] + acc[mi][ni][r];
        }
  }
}

// ------ 256x256 8-phase GEMM ------
#define VM8 asm volatile("s_waitcnt vmcnt(8)" ::: "memory")
#define VM4 asm volatile("s_waitcnt vmcnt(4)" ::: "memory")
#define VM0 asm volatile("s_waitcnt vmcnt(0)" ::: "memory")
#define VMN

#define STGP(buf_, kh_, j_) { \
    char* dA = lds[buf_] + (kh_) * 16384; \
    char* dB = lds[buf_] + 32768 + (kh_) * 16384; \
    u64 ko = (u64)((j_) * 64 + (kh_) * 32) * 2; \
    gload_lds16(Ab0 + ko, dA + t * 16); \
    gload_lds16(Ab1 + ko, dA + 8192 + t * 16); \
    gload_lds16(Bb0 + ko, dB + t * 16); \
    gload_lds16(Bb1 + ko, dB + 8192 + t * 16); }

#define MFMA16(mibase) \
  _Pragma("unroll") for (int mi = 0; mi < 4; ++mi) \
    _Pragma("unroll") for (int ni = 0; ni < 4; ++ni) \
      acc[mi + (mibase)][ni] = __builtin_amdgcn_mfma_f32_16x16x32_bf16(afr[mi], bfr[ni], acc[mi + (mibase)][ni], 0, 0, 0);

#define PH_COMPUTE(mibase) \
  __builtin_amdgcn_s_barrier(); \
  asm volatile("s_waitcnt lgkmcnt(0)" ::: "memory"); \
  __builtin_amdgcn_sched_barrier(0); \
  __builtin_amdgcn_s_setprio(1); \
  MFMA16(mibase); \
  __builtin_amdgcn_s_setprio(0);

#define TILE256(jj, S1, S3, G1, G3) { \
  const int buf_ = (jj) & 1, kf_ = (jj) & 1, ks2_ = kf_ ^ 1; \
  const char* LA_ = lds[buf_]; \
  const char* LB_ = lds[buf_] + 32768; \
  bf16x8 afr[4], bfr[4]; \
  _Pragma("unroll") for (int ni = 0; ni < 4; ++ni) \
    bfr[ni] = frag_read(LB_ + kf_ * 16384, wn * 64 + ni * 16 + lr, lq); \
  _Pragma("unroll") for (int mi = 0; mi < 4; ++mi) \
    afr[mi] = frag_read(LA_ + kf_ * 16384, wm * 128 + mi * 16 + lr, lq); \
  PH_COMPUTE(0); \
  __builtin_amdgcn_s_barrier(); \
  _Pragma("unroll") for (int mi = 0; mi < 4; ++mi) \
    afr[mi] = frag_read(LA_ + kf_ * 16384, wm * 128 + (mi + 4) * 16 + lr, lq); \
  if (S1) STGP(buf_ ^ 1, kf_, (jj) + 1); \
  PH_COMPUTE(4); \
  G1; \
  __builtin_amdgcn_s_barrier(); \
  _Pragma("unroll") for (int ni = 0; ni < 4; ++ni) \
    bfr[ni] = frag_read(LB_ + ks2_ * 16384, wn * 64 + ni * 16 + lr, lq); \
  _Pragma("unroll") for (int mi = 0; mi < 4; ++mi) \
    afr[mi] = frag_read(LA_ + ks2_ * 16384, wm * 128 + mi * 16 + lr, lq); \
  PH_COMPUTE(0); \
  __builtin_amdgcn_s_barrier(); \
  _Pragma("unroll") for (int mi = 0; mi < 4; ++mi) \
    afr[mi] = frag_read(LA_ + ks2_ * 16384, wm * 128 + (mi + 4) * 16 + lr, lq); \
  if (S3) STGP(buf_, kf_, (jj) + 2); \
  PH_COMPUTE(4); \
  G3; \
  __builtin_amdgcn_s_barrier(); \
}

// EPI 0: f32 split-K partial; EPI 3: paired silu-gate
template <int EPI>
__global__ __launch_bounds__(512, 2)
void k_g256(const unsigned short* __restrict__ A,
            const unsigned short* __restrict__ Bt,
            void* Cout, int M, int N, int K, int KH) {
  __shared__ char lds[2][65536] __attribute__((aligned(16)));
  int t = threadIdx.x, w = t >> 6, l = t & 63;
  int wm = w >> 2, wn = w & 3;
  int lr = l & 15, lq = l >> 4;
  int gx = gridDim.x;
  int flat = blockIdx.y * gx + blockIdx.x;
  int swzf = xcd_swz(flat, gx * gridDim.y);
  int bm = swzf / gx, bn = swzf % gx;
  int kz = blockIdx.z;
  int NT = KH >> 6;
  int r0 = t >> 2, sl = t & 3;
  int c0 = (sl ^ (r0 & 3)) * 8;
  const unsigned short* Az = A + (u64)kz * KH;
  const unsigned short* Bz = Bt + (u64)kz * KH;
  const char* Ab0 = (const char*)(Az + (u64)(bm * 256 + r0) * K + c0);
  const char* Ab1 = (const char*)(Az + (u64)(bm * 256 + 128 + r0) * K + c0);
  const char* Bb0 = (const char*)(Bz + (u64)(bn * 256 + r0) * K + c0);
  const char* Bb1 = (const char*)(Bz + (u64)(bn * 256 + 128 + r0) * K + c0);
  f32x4 acc[8][4];
#pragma unroll
  for (int i = 0; i < 8; ++i)
#pragma unroll
    for (int j = 0; j < 4; ++j) acc[i][j] = (f32x4){0.f, 0.f, 0.f, 0.f};
  STGP(0, 0, 0);
  STGP(0, 1, 0);
  STGP(1, 1, 1);
  VM8;
  __builtin_amdgcn_s_barrier();
  for (int j = 0; j < NT - 2; ++j) TILE256(j, 1, 1, VM8, VM8);
  TILE256(NT - 2, 1, 0, VM8, VM4);
  TILE256(NT - 1, 0, 0, VM0, VMN);
  u64 zoff = (u64)kz * M * N;
#pragma unroll
  for (int mi = 0; mi < 8; ++mi)
#pragma unroll
    for (int ni = 0; ni < 4; ++ni)
#pragma unroll
      for (int r = 0; r < 4; ++r) {
        int row = bm * 256 + wm * 128 + mi * 16 + lq * 4 + r;
        int col = bn * 256 + wn * 64 + ni * 16 + lr;
        float v = acc[mi][ni][r];
        if (EPI == 3) {
          float pv = __shfl_xor(v, 1);
          if ((lr & 1) == 0) {
            float res = v / (1.f + __expf(-v)) * pv;
            ((unsigned short*)Cout)[(u64)row * (N >> 1) + (col >> 1)] = f2bf(res);
          }
        } else {
          ((float*)Cout)[zoff + (u64)row * N + col] = v;
        }
      }
}

// ------ fused attention: QBLK=128, 8 waves; grid (hh, b, qt) for XCD co-location ------
__global__ __launch_bounds__(512) void k_attn(const unsigned short* __restrict__ qr,
                                              const unsigned short* __restrict__ kr,
                                              const unsigned short* __restrict__ vt,
                                              unsigned short* __restrict__ outp) {
  __shared__ unsigned short Klds[2][2][64 * 32] __attribute__((aligned(16)));
  __shared__ unsigned short Vlds[2][2][64 * 32] __attribute__((aligned(16)));
  __shared__ unsigned short Plds[8][16 * 64] __attribute__((aligned(16)));
  // grid reorder: same-(b,hh) blocks differ in flat id by multiples of 64 -> same XCD
  int hh = blockIdx.x, b = blockIdx.y, qt = blockIdx.z;
  int t = threadIdx.x, w = t >> 6, l = t & 63;
  int lr = l & 15, lq = l >> 4;
  u64 bh = (u64)(b * Hn + hh);
  const unsigned short* Qp = qr + bh * (Ssz * DHn);
  const unsigned short* Kp = kr + bh * (Ssz * DHn);
  const unsigned short* Vp = vt + bh * ((u64)DHn * Ssz);
  int q0 = qt * 128 + w * 16;
  int qlo_ = qt * 128, qhi_ = qt * 128 + 128;
  bf16x8 qlo = *(const bf16x8*)&Qp[(q0 + lr) * DHn + lq * 8];
  bf16x8 qhi = *(const bf16x8*)&Qp[(q0 + lr) * DHn + 32 + lq * 8];
  int u_ = t & 255;
  int srow = u_ >> 2, scol8 = (u_ & 3) * 8;
#define STAGEKV(bufi, kbase)                                                         \
  do {                                                                               \
    if (t < 256) {                                                                   \
      if ((kbase) >= qlo_)                                                           \
        gload_lds16(&Kp[((kbase) + srow) * 64 + scol8],      (char*)&Klds[bufi][0][0] + u_ * 16); \
      if ((kbase) < qhi_)                                                            \
        gload_lds16(&Kp[((kbase) + srow) * 64 + 32 + scol8], (char*)&Klds[bufi][1][0] + u_ * 16); \
    } else {                                                                         \
      gload_lds16(&Vp[(u64)srow * Ssz + (kbase) + scol8],      (char*)&Vlds[bufi][0][0] + u_ * 16); \
      gload_lds16(&Vp[(u64)srow * Ssz + (kbase) + 32 + scol8], (char*)&Vlds[bufi][1][0] + u_ * 16); \
    }                                                                                \
  } while (0)
  float m_col = -1e30f, lsum = 0.f;
  float m_row[4] = {-1e30f, -1e30f, -1e30f, -1e30f};
  f32x4 o[4];
#pragma unroll
  for (int r = 0; r < 4; ++r) o[r] = (f32x4){0.f, 0.f, 0.f, 0.f};
  char* Pw = (char*)&Plds[w][0];

  STAGEKV(0, 0);
  asm volatile("s_waitcnt vmcnt(0)" ::: "memory");
  __syncthreads();
  int buf = 0;
  const float lsc = SCALE_ * LOG2E_;
  for (int kb = 0; kb < Ssz; kb += 64) {
    if (kb + 64 < Ssz) STAGEKV(buf ^ 1, kb + 64);
    float p[4][4];
#pragma unroll
    for (int ct = 0; ct < 4; ++ct) {
      int kc = kb + ct * 16;
      f32x4 z = (f32x4){0.f, 0.f, 0.f, 0.f};
      if (kc < q0) {
        bf16x8 khi = *(const bf16x8*)&Klds[buf][1][(ct * 16 + lr) * 32 + lq * 8];
        f32x4 shi = __builtin_amdgcn_mfma_f32_16x16x32_bf16(khi, qhi, z, 0, 0, 0);
#pragma unroll
        for (int r = 0; r < 4; ++r) p[ct][r] = shi[r] * lsc;
      } else if (kc > q0) {
        bf16x8 klo = *(const bf16x8*)&Klds[buf][0][(ct * 16 + lr) * 32 + lq * 8];
        f32x4 slo = __builtin_amdgcn_mfma_f32_16x16x32_bf16(klo, qlo, z, 0, 0, 0);
#pragma unroll
        for (int r = 0; r < 4; ++r) p[ct][r] = slo[r] * lsc;
      } else {
        bf16x8 klo = *(const bf16x8*)&Klds[buf][0][(ct * 16 + lr) * 32 + lq * 8];
        bf16x8 khi = *(const bf16x8*)&Klds[buf][1][(ct * 16 + lr) * 32 + lq * 8];
        f32x4 slo = __builtin_amdgcn_mfma_f32_16x16x32_bf16(klo, qlo, z, 0, 0, 0);
        f32x4 shi = __builtin_amdgcn_mfma_f32_16x16x32_bf16(khi, qhi, z, 0, 0, 0);
        int kg0 = kc + lq * 4;
        int qg = q0 + lr;
#pragma unroll
        for (int r = 0; r < 4; ++r) p[ct][r] = (kg0 + r <= qg ? shi[r] : slo[r]) * lsc;
      }
    }
    float tm = p[0][0];
#pragma unroll
    for (int ct = 0; ct < 4; ++ct)
#pragma unroll
      for (int r = 0; r < 4; ++r) tm = fmaxf(tm, p[ct][r]);
    tm = fmaxf(tm, __shfl_xor(tm, 16));
    tm = fmaxf(tm, __shfl_xor(tm, 32));
    if (__any(tm > m_col + 8.f)) {
      float m_new = fmaxf(m_col, tm);
      lsum *= exp2f(m_col - m_new);
      m_col = m_new;
#pragma unroll
      for (int r = 0; r < 4; ++r) {
        float mr = __shfl(m_col, lq * 4 + r);
        float scf = exp2f(m_row[r] - mr);
        m_row[r] = mr;
        o[0][r] *= scf; o[1][r] *= scf; o[2][r] *= scf; o[3][r] *= scf;
      }
    }
#pragma unroll
    for (int ct = 0; ct < 4; ++ct) {
      float e0 = exp2f(p[ct][0] - m_col);
      float e1 = exp2f(p[ct][1] - m_col);
      float e2 = exp2f(p[ct][2] - m_col);
      float e3 = exp2f(p[ct][3] - m_col);
      lsum += e0 + e1 + e2 + e3;
      ushort4 pk; pk.x = f2bf(e0); pk.y = f2bf(e1); pk.z = f2bf(e2); pk.w = f2bf(e3);
      int byte_ = (lr * 128 + ct * 32 + lq * 8) ^ ((lr & 7) << 4);
      *(ushort4*)(Pw + byte_) = pk;
    }
    asm volatile("s_waitcnt lgkmcnt(0)" ::: "memory");
    __builtin_amdgcn_sched_barrier(0);
#pragma unroll
    for (int ks = 0; ks < 2; ++ks) {
      int pb = (lr * 128 + ks * 64 + lq * 16) ^ ((lr & 7) << 4);
      bf16x8 pa = *(const bf16x8*)(Pw + pb);
#pragma unroll
      for (int nt = 0; nt < 4; ++nt) {
        bf16x8 vb = *(const bf16x8*)&Vlds[buf][ks][(nt * 16 + lr) * 32 + lq * 8];
        o[nt] = __builtin_amdgcn_mfma_f32_16x16x32_bf16(pa, vb, o[nt], 0, 0, 0);
      }
    }
    asm volatile("s_waitcnt vmcnt(0)" ::: "memory");
    __syncthreads();
    buf ^= 1;
  }
  lsum += __shfl_xor(lsum, 16);
  lsum += __shfl_xor(lsum, 32);
  u64 obase = ((u64)b * Ssz) * Dsz + (u64)hh * DHn;
#pragma unroll
  for (int r = 0; r < 4; ++r) {
    float mr = __shfl(m_col, lq * 4 + r);
    float adj = exp2f(m_row[r] - mr);
    float ls = __shfl(lsum, lq * 4 + r);
    float inv = adj / ls;
    int qrow = q0 + lq * 4 + r;
#pragma unroll
    for (int nt = 0; nt < 4; ++nt)
      outp[obase + (u64)qrow * Dsz + nt * 16 + lr] = f2bf(o[nt][r] * inv);
  }
#undef STAGEKV
}

// ---------------- softmax over S ----------------
__global__ __launch_bounds__(256) void k_softmax_s(const float* __restrict__ sc,
                                                   float* __restrict__ pw) {
  int b = blockIdx.x, t = threadIdx.x;
  const float* sr = sc + b * Ssz;
  float4 v = *(const float4*)&sr[t * 4];
  float mx = fmaxf(fmaxf(v.x, v.y), fmaxf(v.z, v.w));
#pragma unroll
  for (int m = 1; m < 64; m <<= 1) mx = fmaxf(mx, __shfl_xor(mx, m));
  __shared__ float red[4];
  if ((t & 63) == 0) red[t >> 6] = mx;
  __syncthreads();
  mx = fmaxf(fmaxf(red[0], red[1]), fmaxf(red[2], red[3]));
  float e0 = __expf(v.x - mx), e1 = __expf(v.y - mx), e2 = __expf(v.z - mx), e3 = __expf(v.w - mx);
  float sm = e0 + e1 + e2 + e3;
#pragma unroll
  for (int m = 1; m < 64; m <<= 1) sm += __shfl_xor(sm, m);
  __shared__ float red2[4];
  if ((t & 63) == 0) red2[t >> 6] = sm;
  __syncthreads();
  sm = red2[0] + red2[1] + red2[2] + red2[3];
  float inv = 1.f / sm;
  float4 o; o.x = e0 * inv; o.y = e1 * inv; o.z = e2 * inv; o.w = e3 * inv;
  *(float4*)&pw[b * Ssz + t * 4] = o;
}

// ------- pooled, two-stage -------
__global__ __launch_bounds__(256) void k_pool1(const float* __restrict__ hf,
                                               const float* __restrict__ pw,
                                               float* __restrict__ part) {
  int d = blockIdx.x * 256 + threadIdx.x;
  int b = blockIdx.y, scn = blockIdx.z;
  const float* pwb = pw + b * Ssz + scn * 64;
  const float* hb = hf + ((u64)(b * Ssz + scn * 64)) * Dsz + d;
  float acc = 0.f;
#pragma unroll 4
  for (int s = 0; s < 64; ++s) acc += pwb[s] * hb[(u64)s * Dsz];
  part[(u64)(b * 16 + scn) * Dsz + d] = acc;
}
__global__ __launch_bounds__(256) void k_pool2(const float* __restrict__ part,
                                               float* __restrict__ pooled) {
  int d = blockIdx.x * 256 + threadIdx.x;
  int b = blockIdx.y;
  float acc = 0.f;
#pragma unroll
  for (int i = 0; i < 16; ++i) acc += part[(u64)(b * 16 + i) * Dsz + d];
  pooled[b * Dsz + d] = acc;
}

// ------- classifier, split-K two-stage -------
__global__ __launch_bounds__(256) void k_cls1(const float* __restrict__ pooled,
                                              const float* __restrict__ wcls,
                                              float* __restrict__ part) {
  int n = blockIdx.x * 64 + (threadIdx.x & 63);
  int b = threadIdx.x >> 6;
  int kz = blockIdx.y;
  const float* pb = pooled + b * Dsz + kz * 128;
  const float* wb = wcls + (u64)(kz * 128) * Ssz + n;
  float acc = 0.f;
#pragma unroll 4
  for (int k = 0; k < 128; ++k) acc += pb[k] * wb[(u64)k * Ssz];
  part[(u64)(kz * 4 + b) * Ssz + n] = acc;
}
__global__ __launch_bounds__(256) void k_cls2(const float* __restrict__ part,
                                              float* __restrict__ outp) {
  int n = blockIdx.x * 64 + (threadIdx.x & 63);
  int b = threadIdx.x >> 6;
  float acc = 0.f;
#pragma unroll
  for (int kz = 0; kz < 8; ++kz) acc += part[(u64)(kz * 4 + b) * Ssz + n];
  outp[b * Ssz + n] = acc;
}

extern "C" void kernel_launch(void* const* d_in, const int* in_sizes, int n_in,
                              void* d_out, int out_size, void* d_ws, size_t ws_size,
                              hipStream_t stream) {
  (void)in_sizes; (void)n_in; (void)out_size; (void)ws_size;
  const int*   tokens  = (const int*)  d_in[0];
  const float* tok_emb = (const float*)d_in[1];
  const float* ln1_s   = (const float*)d_in[2];
  const float* ln1_b   = (const float*)d_in[3];
  const float* w_qkv   = (const float*)d_in[4];
  const float* w_proj  = (const float*)d_in[5];
  const float* ln2_s   = (const float*)d_in[6];
  const float* ln2_b   = (const float*)d_in[7];
  const float* w_in    = (const float*)d_in[8];
  const float* w_out   = (const float*)d_in[9];
  const float* lnf_s   = (const float*)d_in[10];
  const float* lnf_b   = (const float*)d_in[11];
  const float* w_score = (const float*)d_in[12];
  const float* w_cls   = (const float*)d_in[13];
  float* outp = (float*)d_out;
  char* ws = (char*)d_ws;

  unsigned short* q_r    = (unsigned short*)(ws + 25165824ull);
  unsigned short* k_r    = (unsigned short*)(ws + 33554432ull);
  unsigned short* v_t    = (unsigned short*)(ws + 41943040ull);
  unsigned short* a_out  = (unsigned short*)(ws + 50331648ull);
  float*          hf     = (float*)(ws + 0);
  unsigned short* x_ln   = (unsigned short*)(ws + 67108864ull);
  unsigned short* mbuf   = (unsigned short*)(ws + 75497472ull);
  float*          h      = (float*)(ws + 109051904ull);
  float* cosT    = (float*)(ws + 125829120ull);
  float* sinT    = (float*)(ws + 125960192ull);
  float* scoresb = (float*)(ws + 126091264ull);
  float* pwb     = (float*)(ws + 126107648ull);
  float* pooledb = (float*)(ws + 126124032ull);
  float* poolpart= (float*)(ws + 126140416ull);
  float* clspart = (float*)(ws + 126402560ull);
  unsigned short* wqkv_t = (unsigned short*)(ws + 134217728ull);
  unsigned short* wproj_t= (unsigned short*)(ws + 171966464ull);
  unsigned short* win_t  = (unsigned short*)(ws + 184549376ull);
  unsigned short* wout_t = (unsigned short*)(ws + 285212672ull);
  float* skpart  = (float*)(ws + 335544320ull);

  dim3 blk(256);
  k_cossin<<<dim3(128), blk, 0, stream>>>(cosT, sinT);
  k_embed_ln<<<dim3(4096), blk, 0, stream>>>(tokens, tok_emb, ln1_s, ln1_b, h, x_ln);
  k_wt<<<dim3(96, 32, 6), blk, 0, stream>>>(w_qkv, wqkv_t, Dsz, 3 * Dsz);
  k_wt<<<dim3(32, 32, 6), blk, 0, stream>>>(w_proj, wproj_t, Dsz, Dsz);
  k_wt_pair<<<dim3(256, 32, 6), blk, 0, stream>>>(w_in, win_t);
  k_wt<<<dim3(32, 128, 6), blk, 0, stream>>>(w_out, wout_t, Fsz, Dsz);

  for (int l = 0; l < Ln; ++l) {
    unsigned short* wq = wqkv_t + (u64)l * 3145728ull;
    unsigned short* wp = wproj_t + (u64)l * 1048576ull;
    unsigned short* wi = win_t + (u64)l * 8388608ull;
    unsigned short* wo = wout_t + (u64)l * 4194304ull;
    k_ring<4><<<dim3(24, 32), blk, 0, stream>>>(x_ln, wq, nullptr, nullptr,
        4096, 3072, 1024, 1024, q_r, k_r, v_t, cosT, sinT);
    // attention grid: (hh, b, qt) so same-(b,hh) q-tiles co-locate on one XCD
    k_attn<<<dim3(16, 4, 8), dim3(512), 0, stream>>>(q_r, k_r, v_t, a_out);
    k_ring<2><<<dim3(8, 32), blk, 0, stream>>>(a_out, wp, h, (void*)h,
        4096, 1024, 1024, 1024, nullptr, nullptr, nullptr, nullptr, nullptr);
    k_layernorm<1><<<dim3(4096), blk, 0, stream>>>(h, ln2_s + l * Dsz, ln2_b + l * Dsz, (void*)x_ln);
    k_g256<3><<<dim3(32, 16), dim3(512), 0, stream>>>(x_ln, wi, (void*)mbuf,
        4096, 8192, 1024, 1024);
    k_g256<0><<<dim3(4, 16, 4), dim3(512), 0, stream>>>(mbuf, wo, (void*)skpart,
        4096, 1024, 4096, 1024);
    if (l < Ln - 1)
      k_redres_ln<<<dim3(4096), blk, 0, stream>>>(skpart, h,
          ln1_s + (l + 1) * Dsz, ln1_b + (l + 1) * Dsz, x_ln);
    else
      k_redres<<<dim3(4096), blk, 0, stream>>>(skpart, h);
  }

  k_lnf_scores<<<dim3(4096), blk, 0, stream>>>(h, lnf_s, lnf_b, w_score, hf, scoresb);
  k_softmax_s<<<dim3(4), blk, 0, stream>>>(scoresb, pwb);
  k_pool1<<<dim3(4, 4, 16), blk, 0, stream>>>(hf, pwb, poolpart);
  k_pool2<<<dim3(4, 4), blk, 0, stream>>>(poolpart, pooledb);
  k_cls1<<<dim3(16, 8), blk, 0, stream>>>(pooledb, w_cls, clspart);
  k_cls2<<<dim3(16), blk, 0, stream>>>(clspart, outp);
}